// Round 1
// baseline (1241.000 us; speedup 1.0000x reference)
//
#include <hip/hip_runtime.h>

// Problem constants
#define B_    8
#define T_    1024
#define D_    1024
#define H_    16
#define HS_   64
#define E_    8
#define DFF   4096
#define NTOK  8192    // B*T
#define NROW  16384   // NTOK * top-2

typedef unsigned short u16;
typedef unsigned int   u32;
typedef __attribute__((ext_vector_type(8))) short bf8;   // 8 bf16 in 4 VGPRs
typedef __attribute__((ext_vector_type(4))) float f4;    // MFMA accumulator

__device__ __forceinline__ u16 f2bf(float f) {
  u32 u = __float_as_uint(f);
  u32 r = (u + 0x7FFFu + ((u >> 16) & 1u)) >> 16;  // RNE
  return (u16)r;
}
__device__ __forceinline__ float bf2f(u16 h) {
  return __uint_as_float(((u32)h) << 16);
}

__device__ __forceinline__ f4 mfma16(bf8 a, bf8 b, f4 c) {
  return __builtin_amdgcn_mfma_f32_16x16x32_bf16(a, b, c, 0, 0, 0);
}

// async global->LDS, 16B per lane; LDS dest = wave-uniform base + lane*16
typedef const __attribute__((address_space(1))) void* gas_ptr;
typedef __attribute__((address_space(3))) void* las_ptr;
__device__ __forceinline__ void async16(const void* g, void* l) {
  __builtin_amdgcn_global_load_lds((gas_ptr)g, (las_ptr)l, 16, 0, 0);
}

// raw barrier (no implicit vmcnt drain) with compiler memory fences
__device__ __forceinline__ void bar() {
  asm volatile("" ::: "memory");
  __builtin_amdgcn_s_barrier();
  asm volatile("" ::: "memory");
}

// ---------------------------------------------------------------- converts
__global__ __launch_bounds__(256) void cvt_x_kernel(const float* __restrict__ x,
                                                    u16* __restrict__ xbf) {
  int i = blockIdx.x * 256 + threadIdx.x;  // float4 index
  float4 v = ((const float4*)x)[i];
  ushort4 o;
  o.x = f2bf(v.x); o.y = f2bf(v.y); o.z = f2bf(v.z); o.w = f2bf(v.w);
  ((ushort4*)xbf)[i] = o;
}

// src fp32 [R x C] -> dst bf16 [C x R], batched along z
__global__ __launch_bounds__(256) void transpose_cvt_kernel(
    const float* __restrict__ src, u16* __restrict__ dst,
    int R, int C, size_t sStride, size_t dStride) {
  __shared__ float t[32][33];
  src += (size_t)blockIdx.z * sStride;
  dst += (size_t)blockIdx.z * dStride;
  int r0 = blockIdx.x * 32, c0 = blockIdx.y * 32;
  int tx = threadIdx.x & 31, ty = threadIdx.x >> 5;  // ty 0..7
#pragma unroll
  for (int i = 0; i < 32; i += 8)
    t[ty + i][tx] = src[(size_t)(r0 + ty + i) * C + (c0 + tx)];
  __syncthreads();
#pragma unroll
  for (int i = 0; i < 32; i += 8)
    dst[(size_t)(c0 + ty + i) * R + (r0 + tx)] = f2bf(t[tx][ty + i]);
}

// V plane [t][c] -> Vt [bh][c][t] (bf16), for PV B-operand staging
__global__ __launch_bounds__(256) void vtrans_kernel(const u16* __restrict__ qkv,
                                                     u16* __restrict__ Vt) {
  __shared__ u16 t[32][33];
  int bh = blockIdx.z, b = bh >> 4, h = bh & 15;
  const u16* Vg = qkv + (size_t)(32 + h) * NTOK * HS_ + (size_t)b * T_ * HS_;
  u16* Vp = Vt + (size_t)bh * HS_ * T_;
  int t0 = blockIdx.x * 32, c0 = blockIdx.y * 32;
  int tx = threadIdx.x & 31, ty = threadIdx.x >> 5;
#pragma unroll
  for (int i = 0; i < 32; i += 8)
    t[ty + i][tx] = Vg[(size_t)(t0 + ty + i) * HS_ + c0 + tx];
  __syncthreads();
#pragma unroll
  for (int i = 0; i < 32; i += 8)
    Vp[(size_t)(c0 + ty + i) * T_ + t0 + tx] = t[tx][ty + i];
}

// ---------------------------------------------------------------- gating
// exact fp32 gating so top-2 selection matches the reference
__global__ __launch_bounds__(256) void gating_kernel(
    const float* __restrict__ x, const float* __restrict__ Wg,
    int* __restrict__ sel, float* __restrict__ wgt) {
  int wave = threadIdx.x >> 6, lane = threadIdx.x & 63;
  int t = blockIdx.x * 4 + wave;
  int e = lane & 7, grp = lane >> 3;
  const float* xr = x + (size_t)t * D_;
  float acc = 0.f;
  for (int i = 0; i < 128; ++i) {
    int d = grp + i * 8;
    acc += xr[d] * Wg[d * 8 + e];
  }
  acc += __shfl_xor(acc, 8);
  acc += __shfl_xor(acc, 16);
  acc += __shfl_xor(acc, 32);
  float lg[8];
#pragma unroll
  for (int j = 0; j < 8; ++j) lg[j] = __shfl(acc, j);
  int s0 = 0; float v0 = lg[0];
#pragma unroll
  for (int j = 1; j < 8; ++j) if (lg[j] > v0) { v0 = lg[j]; s0 = j; }
  int s1 = -1; float v1 = -3.4e38f;
#pragma unroll
  for (int j = 0; j < 8; ++j) if (j != s0 && lg[j] > v1) { v1 = lg[j]; s1 = j; }
  if (lane == 0) {
    float dd = __expf(v1 - v0);
    float w0 = 1.f / (1.f + dd);
    sel[2 * t]     = s0; sel[2 * t + 1] = s1;
    wgt[2 * t]     = w0; wgt[2 * t + 1] = dd * w0;
  }
}

// meta[0..7]=counts, meta[8..15]=row offsets, meta[16..23]=128-block prefix,
// meta[24]=total 128-blocks, meta[32..39]=256-block prefix, meta[40]=total 256-blocks
__global__ __launch_bounds__(256) void offsets_kernel(const int* __restrict__ sel,
                                                      int* __restrict__ meta) {
  __shared__ int hist[E_];
  int tid = threadIdx.x;
  if (tid < E_) hist[tid] = 0;
  __syncthreads();
  for (int i = tid; i < NROW; i += 256) atomicAdd(&hist[sel[i]], 1);
  __syncthreads();
  if (tid == 0) {
    int s = 0, mb = 0, mb2 = 0;
    for (int e = 0; e < E_; ++e) {
      int c = hist[e];
      meta[e] = c; meta[8 + e] = s; meta[16 + e] = mb; meta[32 + e] = mb2;
      s += c; mb += (c + 127) >> 7; mb2 += (c + 255) >> 8;
    }
    meta[24] = mb;
    meta[40] = mb2;
  }
}

// deterministic per-expert stable assignment via ballot scan
__global__ __launch_bounds__(256) void assign_kernel(
    const int* __restrict__ sel, const float* __restrict__ wgt,
    const int* __restrict__ meta, int* __restrict__ gidx,
    float* __restrict__ gw, int* __restrict__ rowmap) {
  int e = blockIdx.x, tid = threadIdx.x, lane = tid & 63, wv = tid >> 6;
  __shared__ int wsum[4];
  __shared__ int carry;
  if (tid == 0) carry = meta[8 + e];
  __syncthreads();
  for (int base = 0; base < NROW; base += 256) {
    int idx = base + tid;
    int f = (sel[idx] == e) ? 1 : 0;
    unsigned long long mask = __ballot(f);
    int pre = __popcll(mask & ((1ull << lane) - 1ull));
    if (lane == 0) wsum[wv] = __popcll(mask);
    __syncthreads();
    int woff = 0;
    for (int w = 0; w < wv; ++w) woff += wsum[w];
    int cb = carry;
    if (f) {
      int pos = cb + woff + pre;
      gidx[pos] = idx >> 1;
      gw[pos] = wgt[idx];
      rowmap[idx] = pos;
    }
    __syncthreads();
    if (tid == 0) carry = cb + wsum[0] + wsum[1] + wsum[2] + wsum[3];
    __syncthreads();
  }
}

// ---------------------------------------------------------------- GEMM (bf16 MFMA, 256^2 8-wave phase-split)
// C[m][n] = sum_k A[m][k] * Bt[n][k]; tile 256x256, BK=64, 8 waves as 2x4,
// each wave 128x64 output = acc[8][4]. LDS: 2x double-buffered 256x64 panels
// for A and B (128 KiB). Staging via global_load_lds width-16 with the proven
// XOR source-swizzle (LDS[row][chunk] holds logical chunk^(row&7); staging lane
// fetches global chunk (l&7)^(l>>3); reads XOR with row&7 -> conflict-free).
//
// Per K-tile: 4 phases x {ds_read frags, stage one half-panel (2 loads/thread),
// raw s_barrier, setprio(1), 16 MFMA, setprio(0), raw s_barrier}. Staging is
// staggered so the per-tile boundary wait is vmcnt(2) (never 0):
//   ph0: stage A(t+1) rows128-255 -> As[c^1]   (As[c^1] dead since tile t-1)
//   ph1: stage B(t+1) rows0-127   -> Bs[c^1]
//   ph2: stage B(t+1) rows128-255 -> Bs[c^1]
//   ph3: stage A(t+2) rows0-127   -> As[c]     (As[c] last read in ph2)
// At tile end, vmcnt(2) leaves only ph3's 2 loads in flight; everything tile
// t+1 needs is forced complete. Race-free: no phase stages a region read in
// the same phase; all reuse is separated by >=1 barrier.
//
// MODE 0: QKV  A=xbf[8192x1024], Bt=wqkvt[3072x1024], out planes qkv[48][8192][64]
// MODE 1: MoE1 A=xbf gathered via gidx, Bt=w1t[e], out H bf16 (+bias,relu)
// MODE 2: MoE2 A=Hbuf rows, Bt=w2t[e], out Y bf16 (+bias)
template <int MODE>
__global__ __launch_bounds__(512, 2) void gemm256(
    const u16* __restrict__ A, const u16* __restrict__ Bt,
    u16* __restrict__ outB, const float* __restrict__ bias,
    const int* __restrict__ meta, const int* __restrict__ gidx, int K) {
  int n0 = blockIdx.y * 256;
  int n_e = 0, off = 0, m0, e = 0;
  const u16* Ap = A;
  const u16* Bp = Bt;
  if constexpr (MODE != 0) {
    int xb = blockIdx.x;
#pragma unroll
    for (int j = 1; j < 8; ++j) if (meta[32 + j] <= xb) e = j;
    n_e = meta[e];
    off = meta[8 + e];
    m0 = (xb - meta[32 + e]) * 256;
    if (m0 >= n_e) return;  // also catches xb >= meta[40]
    if constexpr (MODE == 1) {
      Bp = Bt + (size_t)e * DFF * 1024;
    } else {
      Ap = A + (size_t)off * DFF;
      Bp = Bt + (size_t)e * 1024 * DFF;
    }
  } else {
    m0 = blockIdx.x * 256;
  }

  __shared__ __align__(16) u16 As[2][256 * 64];   // 64 KiB
  __shared__ __align__(16) u16 Bs[2][256 * 64];   // 64 KiB

  int tid = threadIdx.x, lane = tid & 63, w = tid >> 6;  // 8 waves
  int wm = w >> 2, wn = w & 3;
  int ml = lane & 15, quad = lane >> 4;
  int lrow = lane >> 3;                      // 0..7
  int gcol = ((lane & 7) ^ lrow) * 8;        // source-swizzled chunk col (u16)

  // per-lane global row pointers for the 4 staging slices (64 rows each)
  const u16* aptr[4];
  const u16* bptr[4];
#pragma unroll
  for (int i = 0; i < 4; ++i) {
    int ra = m0 + i * 64 + w * 8 + lrow;
    if constexpr (MODE == 1) {
      int rr = ra < n_e ? ra : n_e - 1;
      aptr[i] = Ap + (size_t)gidx[off + rr] * 1024 + gcol;
    } else if constexpr (MODE == 2) {
      int rr = ra < n_e ? ra : n_e - 1;
      aptr[i] = Ap + (size_t)rr * DFF + gcol;
    } else {
      aptr[i] = Ap + (size_t)ra * 1024 + gcol;
    }
    bptr[i] = Bp + (size_t)(n0 + i * 64 + w * 8 + lrow) * K + gcol;
  }

  const int NT = K >> 6;

  // stage half h (rows h*128..h*128+127) of K-tile t into buffer buf
  auto stA = [&](int buf, int t, int h) {
#pragma unroll
    for (int j = 0; j < 2; ++j) {
      int i = h * 2 + j;
      async16(aptr[i] + t * 64, &As[buf][(i * 64 + w * 8) * 64]);
    }
  };
  auto stB = [&](int buf, int t, int h) {
#pragma unroll
    for (int j = 0; j < 2; ++j) {
      int i = h * 2 + j;
      async16(bptr[i] + t * 64, &Bs[buf][(i * 64 + w * 8) * 64]);
    }
  };

  f4 acc[8][4];
#pragma unroll
  for (int i = 0; i < 8; ++i)
#pragma unroll
    for (int j = 0; j < 4; ++j) acc[i][j] = (f4){0.f, 0.f, 0.f, 0.f};

  // prologue: tile0 fully, tile1 A-half0; leaves exactly 2 loads in flight
  stA(0, 0, 0); stA(0, 0, 1); stB(0, 0, 0); stB(0, 0, 1);
  stA(1, 1, 0);
  asm volatile("s_waitcnt vmcnt(2)" ::: "memory");
  bar();

  int mq = ml & 7;  // row&7 for fragment rows (frag bases are multiples of 8)
  bf8 af[8], bfr[4];

  for (int t = 0; t < NT; ++t) {
    const int c = t & 1;
    const u16* Ac = As[c];
    const u16* Bc = Bs[c];

    // ---- phase 0: read A kk0 (8) + B n0,n1 kk0 (2); stage A(t+1) half1
#pragma unroll
    for (int mi = 0; mi < 8; ++mi)
      af[mi] = *(const bf8*)&Ac[(wm * 128 + mi * 16 + ml) * 64 + ((quad) ^ mq) * 8];
#pragma unroll
    for (int ni = 0; ni < 2; ++ni)
      bfr[ni] = *(const bf8*)&Bc[(wn * 64 + ni * 16 + ml) * 64 + ((quad) ^ mq) * 8];
    if (t + 1 < NT) stA(c ^ 1, t + 1, 1);
    bar();
    __builtin_amdgcn_s_setprio(1);
#pragma unroll
    for (int mi = 0; mi < 8; ++mi) {
      acc[mi][0] = mfma16(af[mi], bfr[0], acc[mi][0]);
      acc[mi][1] = mfma16(af[mi], bfr[1], acc[mi][1]);
    }
    __builtin_amdgcn_s_setprio(0);
    bar();

    // ---- phase 1: read B n2,n3 kk0; stage B(t+1) half0
#pragma unroll
    for (int ni = 2; ni < 4; ++ni)
      bfr[ni] = *(const bf8*)&Bc[(wn * 64 + ni * 16 + ml) * 64 + ((quad) ^ mq) * 8];
    if (t + 1 < NT) stB(c ^ 1, t + 1, 0);
    bar();
    __builtin_amdgcn_s_setprio(1);
#pragma unroll
    for (int mi = 0; mi < 8; ++mi) {
      acc[mi][2] = mfma16(af[mi], bfr[2], acc[mi][2]);
      acc[mi][3] = mfma16(af[mi], bfr[3], acc[mi][3]);
    }
    __builtin_amdgcn_s_setprio(0);
    bar();

    // ---- phase 2: read A kk1 (8) + B n0,n1 kk1 (2); stage B(t+1) half1
#pragma unroll
    for (int mi = 0; mi < 8; ++mi)
      af[mi] = *(const bf8*)&Ac[(wm * 128 + mi * 16 + ml) * 64 + ((4 + quad) ^ mq) * 8];
#pragma unroll
    for (int ni = 0; ni < 2; ++ni)
      bfr[ni] = *(const bf8*)&Bc[(wn * 64 + ni * 16 + ml) * 64 + ((4 + quad) ^ mq) * 8];
    if (t + 1 < NT) stB(c ^ 1, t + 1, 1);
    bar();
    __builtin_amdgcn_s_setprio(1);
#pragma unroll
    for (int mi = 0; mi < 8; ++mi) {
      acc[mi][0] = mfma16(af[mi], bfr[0], acc[mi][0]);
      acc[mi][1] = mfma16(af[mi], bfr[1], acc[mi][1]);
    }
    __builtin_amdgcn_s_setprio(0);
    bar();

    // ---- phase 3: read B n2,n3 kk1; stage A(t+2) half0
#pragma unroll
    for (int ni = 2; ni < 4; ++ni)
      bfr[ni] = *(const bf8*)&Bc[(wn * 64 + ni * 16 + ml) * 64 + ((4 + quad) ^ mq) * 8];
    if (t + 2 < NT) stA(c, t + 2, 0);
    bar();
    __builtin_amdgcn_s_setprio(1);
#pragma unroll
    for (int mi = 0; mi < 8; ++mi) {
      acc[mi][2] = mfma16(af[mi], bfr[2], acc[mi][2]);
      acc[mi][3] = mfma16(af[mi], bfr[3], acc[mi][3]);
    }
    __builtin_amdgcn_s_setprio(0);
    // counted boundary wait: only ph3's 2 staging loads stay in flight
    asm volatile("s_waitcnt vmcnt(2)" ::: "memory");
    bar();
  }

#pragma unroll
  for (int mi = 0; mi < 8; ++mi)
#pragma unroll
    for (int ni = 0; ni < 4; ++ni)
#pragma unroll
      for (int rg = 0; rg < 4; ++rg) {
        int m = m0 + wm * 128 + mi * 16 + quad * 4 + rg;
        int n = n0 + wn * 64 + ni * 16 + ml;
        float v = acc[mi][ni][rg];
        if constexpr (MODE == 0) {
          int pl = n >> 6, col = n & 63;
          outB[(size_t)pl * NTOK * HS_ + (size_t)m * HS_ + col] = f2bf(v);
        } else if constexpr (MODE == 1) {
          if (m < n_e) {
            float hv = v + bias[e * DFF + n];
            outB[(size_t)(off + m) * DFF + n] = f2bf(fmaxf(hv, 0.f));
          }
        } else {
          if (m < n_e) {
            outB[(size_t)(off + m) * 1024 + n] = f2bf(v + bias[e * 1024 + n]);
          }
        }
      }
}

// ---------------------------------------------------------------- attention (bf16 MFMA flash)
__global__ __launch_bounds__(256) void attn_kernel(const u16* __restrict__ qkv,
                                                   const u16* __restrict__ Vt,
                                                   float* __restrict__ attn_out) {
  int qt = blockIdx.x, bh = blockIdx.y;
  int b = bh >> 4, h = bh & 15;
  int q0 = qt * 64;
  const u16* Qg = qkv + (size_t)h * NTOK * HS_ + (size_t)b * T_ * HS_;
  const u16* Kg = qkv + (size_t)(16 + h) * NTOK * HS_ + (size_t)b * T_ * HS_;
  const u16* Vp = Vt + (size_t)bh * HS_ * T_;
  __shared__ __align__(16) u16 Qs[64 * 72];
  __shared__ __align__(16) u16 Ks[64 * 72];
  __shared__ __align__(16) u16 Vs[64 * 72];   // Vs[c][j]
  __shared__ __align__(16) u16 Ps[64 * 72];   // wave w uses rows w*16..w*16+15
  int tid = threadIdx.x, lane = tid & 63, wave = tid >> 6;
  int ml = lane & 15, quad = lane >> 4;

  for (int i = tid; i < 512; i += 256) {
    int r = i >> 3, c = (i & 7) * 8;
    *(uint4*)&Qs[r * 72 + c] = *(const uint4*)(Qg + (size_t)(q0 + r) * HS_ + c);
  }

  f4 acc_o[4];
  float m_[4], l_[4];
#pragma unroll
  for (int i = 0; i < 4; ++i) {
    acc_o[i] = (f4){0.f, 0.f, 0.f, 0.f};
    m_[i] = -1e30f; l_[i] = 0.f;
  }

  for (int ck = 0; ck <= qt; ++ck) {
    int kv0 = ck * 64;
    __syncthreads();
    for (int i = tid; i < 512; i += 256) {
      int r = i >> 3, c = (i & 7) * 8;
      *(uint4*)&Ks[r * 72 + c] = *(const uint4*)(Kg + (size_t)(kv0 + r) * HS_ + c);
      *(uint4*)&Vs[r * 72 + c] = *(const uint4*)(Vp + (size_t)r * T_ + kv0 + c);
    }
    __syncthreads();

    // S = Q K^T (16x64 per wave)
    f4 sacc[4];
#pragma unroll
    for (int nt = 0; nt < 4; ++nt) sacc[nt] = (f4){0.f, 0.f, 0.f, 0.f};
#pragma unroll
    for (int kk = 0; kk < 64; kk += 32) {
      bf8 a = *(const bf8*)&Qs[(wave * 16 + ml) * 72 + kk + quad * 8];
#pragma unroll
      for (int nt = 0; nt < 4; ++nt) {
        bf8 bk = *(const bf8*)&Ks[(nt * 16 + ml) * 72 + kk + quad * 8];
        sacc[nt] = mfma16(a, bk, sacc[nt]);
      }
    }

    // online softmax; C-layout: row = quad*4+rg (strip-local), col = nt*16+ml
    bool dm = (kv0 == q0);  // only the diagonal chunk needs masking
    float pv[4][4], mx[4];
#pragma unroll
    for (int rg = 0; rg < 4; ++rg) {
      int gq = q0 + wave * 16 + quad * 4 + rg;
      float mm = -1e30f;
#pragma unroll
      for (int nt = 0; nt < 4; ++nt) {
        float s = sacc[nt][rg] * 0.03125f;  // D^-0.5
        if (dm && (kv0 + nt * 16 + ml) > gq) s = -1e30f;
        pv[nt][rg] = s;
        mm = fmaxf(mm, s);
      }
      mx[rg] = mm;
    }
#pragma unroll
    for (int off = 1; off < 16; off <<= 1)
#pragma unroll
      for (int rg = 0; rg < 4; ++rg) mx[rg] = fmaxf(mx[rg], __shfl_xor(mx[rg], off));

    float al[4], rs[4];
#pragma unroll
    for (int rg = 0; rg < 4; ++rg) {
      float mn = fmaxf(m_[rg], mx[rg]);
      al[rg] = __expf(m_[rg] - mn);
      m_[rg] = mn;
      float r = 0.f;
#pragma unroll
      for (int nt = 0; nt < 4; ++nt) {
        float ev = __expf(pv[nt][rg] - mn);
        pv[nt][rg] = ev;
        r += ev;
      }
      rs[rg] = r;
    }
#pragma unroll
    for (int off = 1; off < 16; off <<= 1)
#pragma unroll
      for (int rg = 0; rg < 4; ++rg) rs[rg] += __shfl_xor(rs[rg], off);

#pragma unroll
    for (int rg = 0; rg < 4; ++rg) {
      l_[rg] = al[rg] * l_[rg] + rs[rg];
#pragma unroll
      for (int nt = 0; nt < 4; ++nt) {
        acc_o[nt][rg] *= al[rg];
        Ps[(wave * 16 + quad * 4 + rg) * 72 + nt * 16 + ml] = f2bf(pv[nt][rg]);
      }
    }

    // PV: A = Ps strip (wave-local; in-wave LDS ordering suffices), B = Vs
#pragma unroll
    for (int kk = 0; kk < 64; kk += 32) {
      bf8 a = *(const bf8*)&Ps[(wave * 16 + ml) * 72 + kk + quad * 8];
#pragma unroll
      for (int ci = 0; ci < 4; ++ci) {
        bf8 bv = *(const bf8*)&Vs[(ci * 16 + ml) * 72 + kk + quad * 8];
        acc_o[ci] = mfma16(a, bv, acc_o[ci]);
      }
    }
  }

#pragma unroll
  for (int rg = 0; rg < 4; ++rg) {
    float inv = 1.f / l_[rg];
    int gq = q0 + wave * 16 + quad * 4 + rg;
    float* orow = attn_out + (size_t)(b * T_ + gq) * D_ + h * HS_;
#pragma unroll
    for (int ci = 0; ci < 4; ++ci) orow[ci * 16 + ml] = acc_o[ci][rg] * inv;
  }
}

// ---------------------------------------------------------------- final: out = x + LN(attn) + LN(moe)
__global__ __launch_bounds__(256) void final_kernel(
    const float* __restrict__ x, const float* __restrict__ attn,
    const u16* __restrict__ Y, const int* __restrict__ rowmap,
    const float* __restrict__ wgt,
    const float* __restrict__ g1, const float* __restrict__ be1,
    const float* __restrict__ g2, const float* __restrict__ be2,
    float* __restrict__ out) {
  int t = blockIdx.x, tid = threadIdx.x;
  int lane = tid & 63, wave = tid >> 6;
  float4 av = ((const float4*)(attn + (size_t)t * D_))[tid];
  int r0 = rowmap[2 * t], r1 = rowmap[2 * t + 1];
  float w0 = wgt[2 * t], w1 = wgt[2 * t + 1];
  ushort4 y0 = ((const ushort4*)(Y + (size_t)r0 * D_))[tid];
  ushort4 y1 = ((const ushort4*)(Y + (size_t)r1 * D_))[tid];
  float4 mv;
  mv.x = w0 * bf2f(y0.x) + w1 * bf2f(y1.x);
  mv.y = w0 * bf2f(y0.y) + w1 * bf2f(y1.y);
  mv.z = w0 * bf2f(y0.z) + w1 * bf2f(y1.z);
  mv.w = w0 * bf2f(y0.w) + w1 * bf2f(y1.w);

  float sa = av.x + av.y + av.z + av.w;
  float qa = av.x * av.x + av.y * av.y + av.z * av.z + av.w * av.w;
  float sm = mv.x + mv.y + mv.z + mv.w;
  float qm = mv.x * mv.x + mv.y * mv.y + mv.z * mv.z + mv.w * mv.w;
#pragma unroll
  for (int off = 1; off < 64; off <<= 1) {
    sa += __shfl_xor(sa, off);
    qa += __shfl_xor(qa, off);
    sm += __shfl_xor(sm, off);
    qm += __shfl_xor(qm, off);
  }
  __shared__ float red[4][4];
  if (lane == 0) { red[wave][0] = sa; red[wave][1] = qa; red[wave][2] = sm; red[wave][3] = qm; }
  __syncthreads();
  sa = red[0][0] + red[1][0] + red[2][0] + red[3][0];
  qa = red[0][1] + red[1][1] + red[2][1] + red[3][1];
  sm = red[0][2] + red[1][2] + red[2][2] + red[3][2];
  qm = red[0][3] + red[1][3] + red[2][3] + red[3][3];
  const float inv_d = 1.f / 1024.f;
  float mu1 = sa * inv_d, var1 = qa * inv_d - mu1 * mu1;
  float mu2 = sm * inv_d, var2 = qm * inv_d - mu2 * mu2;
  float rs1 = rsqrtf(var1 + 1e-5f), rs2 = rsqrtf(var2 + 1e-5f);

  float4 xv = ((const float4*)(x + (size_t)t * D_))[tid];
  float4 g1v = ((const float4*)g1)[tid], b1v = ((const float4*)be1)[tid];
  float4 g2v = ((const float4*)g2)[tid], b2v = ((const float4*)be2)[tid];
  float4 o;
  o.x = xv.x + (av.x - mu1) * rs1 * g1v.x + b1v.x + (mv.x - mu2) * rs2 * g2v.x + b2v.x;
  o.y = xv.y + (av.y - mu1) * rs1 * g1v.y + b1v.y + (mv.y - mu2) * rs2 * g2v.y + b2v.y;
  o.z = xv.z + (av.z - mu1) * rs1 * g1v.z + b1v.z + (mv.z - mu2) * rs2 * g2v.z + b2v.z;
  o.w = xv.w + (av.w - mu1) * rs1 * g1v.w + b1v.w + (mv.w - mu2) * rs2 * g2v.w + b2v.w;
  ((float4*)(out + (size_t)t * D_))[tid] = o;
}

// ---------------------------------------------------------------- launch
extern "C" void kernel_launch(void* const* d_in, const int* in_sizes, int n_in,
                              void* d_out, int out_size, void* d_ws, size_t ws_size,
                              hipStream_t stream) {
  const float* x   = (const float*)d_in[0];
  const float* Wq  = (const float*)d_in[1];
  const float* Wk  = (const float*)d_in[2];
  const float* Wv  = (const float*)d_in[3];
  const float* Wg  = (const float*)d_in[4];
  const float* W1  = (const float*)d_in[5];
  const float* b1  = (const float*)d_in[6];
  const float* W2  = (const float*)d_in[7];
  const float* b2  = (const float*)d_in[8];
  const float* g1  = (const float*)d_in[9];
  const float* be1 = (const float*)d_in[10];
  const float* g2  = (const float*)d_in[11];
  const float* be2 = (const float*)d_in[12];
  float* out = (float*)d_out;

  char* ws = (char*)d_ws;
  size_t off = 0;
  auto alloc = [&](size_t bytes) -> void* {
    void* p = ws + off;
    off = (off + bytes + 255) & ~(size_t)255;
    return p;
  };
  u16*   xbf    = (u16*)alloc((size_t)NTOK * D_ * 2);          // 16.8 MB
  u16*   wqkvt  = (u16*)alloc((size_t)48 * 64 * 1024 * 2);     // 6.3 MB  [3072][1024]
  u16*   w1t    = (u16*)alloc((size_t)E_ * DFF * 1024 * 2);    // 67 MB   [e][4096][1024]
  u16*   w2t    = (u16*)alloc((size_t)E_ * 1024 * DFF * 2);    // 67 MB   [e][1024][4096]
  u16*   qkv    = (u16*)alloc((size_t)48 * NTOK * HS_ * 2);    // 50 MB   [mat*16+h][8192][64]
  float* attn   = (float*)alloc((size_t)NTOK * D_ * 4);        // 33.5 MB
  u16*   Hbuf   = (u16*)alloc((size_t)NROW * DFF * 2);         // 134 MB
  u16*   Ybuf   = (u16*)alloc((size_t)NROW * 1024 * 2);        // 33.5 MB
  int*   meta   = (int*)alloc(256);
  int*   sel    = (int*)alloc(NROW * 4);
  float* wgt    = (float*)alloc(NROW * 4);
  int*   gidx   = (int*)alloc(NROW * 4);
  float* gw     = (float*)alloc(NROW * 4);
  int*   rowmap = (int*)alloc(NROW * 4);
  // Vt aliases Hbuf: consumed by attn_kernel before gemm256<1> writes Hbuf.
  u16*   Vt     = Hbuf;  // 16.7 MB [bh][64][1024]
  (void)ws_size; (void)in_sizes; (void)n_in; (void)out_size; (void)gw;

  // dtype converts / transposes (weights -> bf16, K-contiguous "B^T" layout)
  cvt_x_kernel<<<NTOK * D_ / 1024, 256, 0, stream>>>(x, xbf);
  transpose_cvt_kernel<<<dim3(32, 2, 16), 256, 0, stream>>>(Wq, wqkvt, 1024, 64, 65536, 65536);
  transpose_cvt_kernel<<<dim3(32, 2, 16), 256, 0, stream>>>(Wk, wqkvt + 16 * 65536, 1024, 64, 65536, 65536);
  transpose_cvt_kernel<<<dim3(32, 2, 16), 256, 0, stream>>>(Wv, wqkvt + 32 * 65536, 1024, 64, 65536, 65536);
  transpose_cvt_kernel<<<dim3(32, 128, 8), 256, 0, stream>>>(W1, w1t, 1024, 4096, (size_t)1024 * 4096, (size_t)1024 * 4096);
  transpose_cvt_kernel<<<dim3(128, 32, 8), 256, 0, stream>>>(W2, w2t, 4096, 1024, (size_t)4096 * 1024, (size_t)4096 * 1024);

  // routing
  gating_kernel<<<NTOK / 4, 256, 0, stream>>>(x, Wg, sel, wgt);
  offsets_kernel<<<1, 256, 0, stream>>>(sel, meta);
  assign_kernel<<<E_, 256, 0, stream>>>(sel, wgt, meta, gidx, gw, rowmap);

  // attention branch: QKV as one 8192x3072x1024 GEMM, then V transpose, then flash
  gemm256<0><<<dim3(32, 12), 512, 0, stream>>>(xbf, wqkvt, qkv, nullptr, nullptr, nullptr, 1024);
  vtrans_kernel<<<dim3(32, 2, 128), 256, 0, stream>>>(qkv, Vt);
  attn_kernel<<<dim3(16, 128), 256, 0, stream>>>(qkv, Vt, attn);

  // MoE branch: compacted 256-row m-block grid (worst case 71 = 64 full + 7 partial)
  gemm256<1><<<dim3(72, 16), 512, 0, stream>>>(xbf, w1t, Hbuf, b1, meta, gidx, 1024);
  gemm256<2><<<dim3(72, 4), 512, 0, stream>>>(Hbuf, w2t, Ybuf, b2, meta, gidx, 4096);

  // out = x + LN(attn) + LN(moe)
  final_kernel<<<NTOK, 256, 0, stream>>>(x, attn, Ybuf, rowmap, wgt, g1, be1, g2, be2, out);
}

// Round 2
// 1190.931 us; speedup vs baseline: 1.0420x; 1.0420x over previous
//
#include <hip/hip_runtime.h>

// Problem constants
#define B_    8
#define T_    1024
#define D_    1024
#define H_    16
#define HS_   64
#define E_    8
#define DFF   4096
#define NTOK  8192    // B*T
#define NROW  16384   // NTOK * top-2

typedef unsigned short u16;
typedef unsigned int   u32;
typedef __attribute__((ext_vector_type(8))) short bf8;   // 8 bf16 in 4 VGPRs
typedef __attribute__((ext_vector_type(4))) float f4;    // MFMA accumulator

__device__ __forceinline__ u16 f2bf(float f) {
  u32 u = __float_as_uint(f);
  u32 r = (u + 0x7FFFu + ((u >> 16) & 1u)) >> 16;  // RNE
  return (u16)r;
}
__device__ __forceinline__ float bf2f(u16 h) {
  return __uint_as_float(((u32)h) << 16);
}

__device__ __forceinline__ f4 mfma16(bf8 a, bf8 b, f4 c) {
  return __builtin_amdgcn_mfma_f32_16x16x32_bf16(a, b, c, 0, 0, 0);
}

// async global->LDS, 16B per lane; LDS dest = wave-uniform base + lane*16
typedef const __attribute__((address_space(1))) void* gas_ptr;
typedef __attribute__((address_space(3))) void* las_ptr;
__device__ __forceinline__ void async16(const void* g, void* l) {
  __builtin_amdgcn_global_load_lds((gas_ptr)g, (las_ptr)l, 16, 0, 0);
}

// raw barrier (no implicit vmcnt drain) with compiler memory fences
__device__ __forceinline__ void bar() {
  asm volatile("" ::: "memory");
  __builtin_amdgcn_s_barrier();
  asm volatile("" ::: "memory");
}

// ---------------------------------------------------------------- converts
__global__ __launch_bounds__(256) void cvt_x_kernel(const float* __restrict__ x,
                                                    u16* __restrict__ xbf) {
  int i = blockIdx.x * 256 + threadIdx.x;  // float4 index
  float4 v = ((const float4*)x)[i];
  ushort4 o;
  o.x = f2bf(v.x); o.y = f2bf(v.y); o.z = f2bf(v.z); o.w = f2bf(v.w);
  ((ushort4*)xbf)[i] = o;
}

// src fp32 [R x C] -> dst bf16 [C x R], batched along z
__global__ __launch_bounds__(256) void transpose_cvt_kernel(
    const float* __restrict__ src, u16* __restrict__ dst,
    int R, int C, size_t sStride, size_t dStride) {
  __shared__ float t[32][33];
  src += (size_t)blockIdx.z * sStride;
  dst += (size_t)blockIdx.z * dStride;
  int r0 = blockIdx.x * 32, c0 = blockIdx.y * 32;
  int tx = threadIdx.x & 31, ty = threadIdx.x >> 5;  // ty 0..7
#pragma unroll
  for (int i = 0; i < 32; i += 8)
    t[ty + i][tx] = src[(size_t)(r0 + ty + i) * C + (c0 + tx)];
  __syncthreads();
#pragma unroll
  for (int i = 0; i < 32; i += 8)
    dst[(size_t)(c0 + ty + i) * R + (r0 + tx)] = f2bf(t[tx][ty + i]);
}

// V plane [t][c] -> Vt [bh][c][t] (bf16), for PV B-operand staging
__global__ __launch_bounds__(256) void vtrans_kernel(const u16* __restrict__ qkv,
                                                     u16* __restrict__ Vt) {
  __shared__ u16 t[32][33];
  int bh = blockIdx.z, b = bh >> 4, h = bh & 15;
  const u16* Vg = qkv + (size_t)(32 + h) * NTOK * HS_ + (size_t)b * T_ * HS_;
  u16* Vp = Vt + (size_t)bh * HS_ * T_;
  int t0 = blockIdx.x * 32, c0 = blockIdx.y * 32;
  int tx = threadIdx.x & 31, ty = threadIdx.x >> 5;
#pragma unroll
  for (int i = 0; i < 32; i += 8)
    t[ty + i][tx] = Vg[(size_t)(t0 + ty + i) * HS_ + c0 + tx];
  __syncthreads();
#pragma unroll
  for (int i = 0; i < 32; i += 8)
    Vp[(size_t)(c0 + ty + i) * T_ + t0 + tx] = t[tx][ty + i];
}

// ---------------------------------------------------------------- gating
// exact fp32 gating so top-2 selection matches the reference
__global__ __launch_bounds__(256) void gating_kernel(
    const float* __restrict__ x, const float* __restrict__ Wg,
    int* __restrict__ sel, float* __restrict__ wgt) {
  int wave = threadIdx.x >> 6, lane = threadIdx.x & 63;
  int t = blockIdx.x * 4 + wave;
  int e = lane & 7, grp = lane >> 3;
  const float* xr = x + (size_t)t * D_;
  float acc = 0.f;
  for (int i = 0; i < 128; ++i) {
    int d = grp + i * 8;
    acc += xr[d] * Wg[d * 8 + e];
  }
  acc += __shfl_xor(acc, 8);
  acc += __shfl_xor(acc, 16);
  acc += __shfl_xor(acc, 32);
  float lg[8];
#pragma unroll
  for (int j = 0; j < 8; ++j) lg[j] = __shfl(acc, j);
  int s0 = 0; float v0 = lg[0];
#pragma unroll
  for (int j = 1; j < 8; ++j) if (lg[j] > v0) { v0 = lg[j]; s0 = j; }
  int s1 = -1; float v1 = -3.4e38f;
#pragma unroll
  for (int j = 0; j < 8; ++j) if (j != s0 && lg[j] > v1) { v1 = lg[j]; s1 = j; }
  if (lane == 0) {
    float dd = __expf(v1 - v0);
    float w0 = 1.f / (1.f + dd);
    sel[2 * t]     = s0; sel[2 * t + 1] = s1;
    wgt[2 * t]     = w0; wgt[2 * t + 1] = dd * w0;
  }
}

// meta[0..7]=counts, meta[8..15]=row offsets, meta[16..23]=128-block prefix,
// meta[24]=total 128-blocks, meta[32..39]=256-block prefix, meta[40]=total 256-blocks
__global__ __launch_bounds__(256) void offsets_kernel(const int* __restrict__ sel,
                                                      int* __restrict__ meta) {
  __shared__ int hist[E_];
  int tid = threadIdx.x;
  if (tid < E_) hist[tid] = 0;
  __syncthreads();
  for (int i = tid; i < NROW; i += 256) atomicAdd(&hist[sel[i]], 1);
  __syncthreads();
  if (tid == 0) {
    int s = 0, mb = 0, mb2 = 0;
    for (int e = 0; e < E_; ++e) {
      int c = hist[e];
      meta[e] = c; meta[8 + e] = s; meta[16 + e] = mb; meta[32 + e] = mb2;
      s += c; mb += (c + 127) >> 7; mb2 += (c + 255) >> 8;
    }
    meta[24] = mb;
    meta[40] = mb2;
  }
}

// deterministic per-expert stable assignment via ballot scan
__global__ __launch_bounds__(256) void assign_kernel(
    const int* __restrict__ sel, const float* __restrict__ wgt,
    const int* __restrict__ meta, int* __restrict__ gidx,
    float* __restrict__ gw, int* __restrict__ rowmap) {
  int e = blockIdx.x, tid = threadIdx.x, lane = tid & 63, wv = tid >> 6;
  __shared__ int wsum[4];
  __shared__ int carry;
  if (tid == 0) carry = meta[8 + e];
  __syncthreads();
  for (int base = 0; base < NROW; base += 256) {
    int idx = base + tid;
    int f = (sel[idx] == e) ? 1 : 0;
    unsigned long long mask = __ballot(f);
    int pre = __popcll(mask & ((1ull << lane) - 1ull));
    if (lane == 0) wsum[wv] = __popcll(mask);
    __syncthreads();
    int woff = 0;
    for (int w = 0; w < wv; ++w) woff += wsum[w];
    int cb = carry;
    if (f) {
      int pos = cb + woff + pre;
      gidx[pos] = idx >> 1;
      gw[pos] = wgt[idx];
      rowmap[idx] = pos;
    }
    __syncthreads();
    if (tid == 0) carry = cb + wsum[0] + wsum[1] + wsum[2] + wsum[3];
    __syncthreads();
  }
}

// ---------------------------------------------------------------- GEMM (bf16 MFMA, 256^2 8-wave, deep-pipelined)
// C[m][n] = sum_k A[m][k] * Bt[n][k]; tile 256x256, BK=64, 8 waves as 2x4,
// each wave 128x64 output = acc[8][4]. LDS: 2x double-buffered 256x64 panels.
// XOR source-swizzle staging (verified): LDS[row][chunk] holds logical chunk
// ^(row&7); staging lane fetches global chunk (l&7)^(l>>3); reads XOR row&7.
//
// Per K-tile t (buffer c = t&1), 4 phases, 16 MFMA each:
//   ph0: ds_read 12 frags (kk0: A x8, B x4); STAGE B(t+1)->Bs[c^1] (4 loads)
//        [Bs[c^1] last read tile t-1 ph2 -> idle]; bar; MFMA ni0,1.
//   ph1: pure MFMA ni2,3 (kk0 frags already in regs).
//   ph2: ds_read 12 frags (kk1); bar; MFMA ni0,1.
//   ph3: STAGE A(t+2)->As[c] (4 loads) [As[c] last read ph2, barrier-sep];
//        MFMA ni2,3; boundary s_waitcnt vmcnt(4); bar.
// The boundary vmcnt(4) forces A(t+1) (issued tile t-1 ph3, ~5 phases of
// cover) and B(t+1) (issued ph0, ~4 phases) complete, keeps A(t+2)'s 4 loads
// in flight. HBM latency (~600-900cy) << 4 phases of MFMA -> near-zero stall.
// Race-free: every staged region's last ds_read is >=1 barrier before issue,
// and every region's loads are vmcnt-forced before its first ds_read.
//
// MODE 0: QKV  A=xbf[8192x1024], Bt=wqkvt[3072x1024], out planes qkv[48][8192][64]
// MODE 1: MoE1 A=xbf gathered via gidx, Bt=w1t[e], out H bf16 (+bias,relu)
// MODE 2: MoE2 A=Hbuf rows, Bt=w2t[e], out Y bf16 (+bias)
template <int MODE>
__global__ __launch_bounds__(512, 2) void gemm256(
    const u16* __restrict__ A, const u16* __restrict__ Bt,
    u16* __restrict__ outB, const float* __restrict__ bias,
    const int* __restrict__ meta, const int* __restrict__ gidx, int K) {
  int n0 = blockIdx.y * 256;
  int n_e = 0, off = 0, m0, e = 0;
  const u16* Ap = A;
  const u16* Bp = Bt;
  if constexpr (MODE != 0) {
    int xb = blockIdx.x;
#pragma unroll
    for (int j = 1; j < 8; ++j) if (meta[32 + j] <= xb) e = j;
    n_e = meta[e];
    off = meta[8 + e];
    m0 = (xb - meta[32 + e]) * 256;
    if (m0 >= n_e) return;  // also catches xb >= meta[40]
    if constexpr (MODE == 1) {
      Bp = Bt + (size_t)e * DFF * 1024;
    } else {
      Ap = A + (size_t)off * DFF;
      Bp = Bt + (size_t)e * 1024 * DFF;
    }
  } else {
    m0 = blockIdx.x * 256;
  }

  __shared__ __align__(16) u16 As[2][256 * 64];   // 64 KiB
  __shared__ __align__(16) u16 Bs[2][256 * 64];   // 64 KiB

  int tid = threadIdx.x, lane = tid & 63, w = tid >> 6;  // 8 waves
  int wm = w >> 2, wn = w & 3;
  int ml = lane & 15, quad = lane >> 4;
  int lrow = lane >> 3;                      // 0..7
  int gcol = ((lane & 7) ^ lrow) * 8;        // source-swizzled chunk col (u16)

  // per-lane global row pointers for the 4 staging slices (64 rows each)
  const u16* aptr[4];
  const u16* bptr[4];
#pragma unroll
  for (int i = 0; i < 4; ++i) {
    int ra = m0 + i * 64 + w * 8 + lrow;
    if constexpr (MODE == 1) {
      int rr = ra < n_e ? ra : n_e - 1;
      aptr[i] = Ap + (size_t)gidx[off + rr] * 1024 + gcol;
    } else if constexpr (MODE == 2) {
      int rr = ra < n_e ? ra : n_e - 1;
      aptr[i] = Ap + (size_t)rr * DFF + gcol;
    } else {
      aptr[i] = Ap + (size_t)ra * 1024 + gcol;
    }
    bptr[i] = Bp + (size_t)(n0 + i * 64 + w * 8 + lrow) * K + gcol;
  }

  const int NT = K >> 6;

  // stage full 256x64 panel of K-tile t into buffer buf (4 loads per lane)
  auto stA = [&](int buf, int t) {
#pragma unroll
    for (int i = 0; i < 4; ++i)
      async16(aptr[i] + t * 64, &As[buf][(i * 64 + w * 8) * 64]);
  };
  auto stB = [&](int buf, int t) {
#pragma unroll
    for (int i = 0; i < 4; ++i)
      async16(bptr[i] + t * 64, &Bs[buf][(i * 64 + w * 8) * 64]);
  };

  f4 acc[8][4];
#pragma unroll
  for (int i = 0; i < 8; ++i)
#pragma unroll
    for (int j = 0; j < 4; ++j) acc[i][j] = (f4){0.f, 0.f, 0.f, 0.f};

  // prologue: tile0 A+B, tile1 A. vmcnt(4) forces tile0 complete, keeps A(1).
  stA(0, 0); stB(0, 0);
  stA(1, 1);
  asm volatile("s_waitcnt vmcnt(4)" ::: "memory");
  bar();

  int mq = ml & 7;  // row&7 for fragment rows (frag bases are multiples of 8)
  bf8 af[8], bfr[4];

  for (int t = 0; t < NT; ++t) {
    const int c = t & 1;
    const u16* Ac = As[c];
    const u16* Bc = Bs[c];

    // ---- phase 0: read all kk0 frags; stage B(t+1) -> Bs[c^1]
#pragma unroll
    for (int mi = 0; mi < 8; ++mi)
      af[mi] = *(const bf8*)&Ac[(wm * 128 + mi * 16 + ml) * 64 + (quad ^ mq) * 8];
#pragma unroll
    for (int ni = 0; ni < 4; ++ni)
      bfr[ni] = *(const bf8*)&Bc[(wn * 64 + ni * 16 + ml) * 64 + (quad ^ mq) * 8];
    if (t + 1 < NT) stB(c ^ 1, t + 1);
    bar();
    __builtin_amdgcn_s_setprio(1);
#pragma unroll
    for (int mi = 0; mi < 8; ++mi) {
      acc[mi][0] = mfma16(af[mi], bfr[0], acc[mi][0]);
      acc[mi][1] = mfma16(af[mi], bfr[1], acc[mi][1]);
    }
    __builtin_amdgcn_s_setprio(0);
    bar();

    // ---- phase 1: pure MFMA (kk0, ni2,3)
    __builtin_amdgcn_s_setprio(1);
#pragma unroll
    for (int mi = 0; mi < 8; ++mi) {
      acc[mi][2] = mfma16(af[mi], bfr[2], acc[mi][2]);
      acc[mi][3] = mfma16(af[mi], bfr[3], acc[mi][3]);
    }
    __builtin_amdgcn_s_setprio(0);
    bar();

    // ---- phase 2: read all kk1 frags
#pragma unroll
    for (int mi = 0; mi < 8; ++mi)
      af[mi] = *(const bf8*)&Ac[(wm * 128 + mi * 16 + ml) * 64 + ((4 + quad) ^ mq) * 8];
#pragma unroll
    for (int ni = 0; ni < 4; ++ni)
      bfr[ni] = *(const bf8*)&Bc[(wn * 64 + ni * 16 + ml) * 64 + ((4 + quad) ^ mq) * 8];
    bar();
    __builtin_amdgcn_s_setprio(1);
#pragma unroll
    for (int mi = 0; mi < 8; ++mi) {
      acc[mi][0] = mfma16(af[mi], bfr[0], acc[mi][0]);
      acc[mi][1] = mfma16(af[mi], bfr[1], acc[mi][1]);
    }
    __builtin_amdgcn_s_setprio(0);
    bar();

    // ---- phase 3: stage A(t+2) -> As[c]; MFMA (kk1, ni2,3); boundary wait
    if (t + 2 < NT) stA(c, t + 2);
    __builtin_amdgcn_s_setprio(1);
#pragma unroll
    for (int mi = 0; mi < 8; ++mi) {
      acc[mi][2] = mfma16(af[mi], bfr[2], acc[mi][2]);
      acc[mi][3] = mfma16(af[mi], bfr[3], acc[mi][3]);
    }
    __builtin_amdgcn_s_setprio(0);
    if (t + 1 < NT) {
      if (t + 2 < NT) {
        asm volatile("s_waitcnt vmcnt(4)" ::: "memory");
      } else {
        asm volatile("s_waitcnt vmcnt(0)" ::: "memory");
      }
    }
    bar();
  }

#pragma unroll
  for (int mi = 0; mi < 8; ++mi)
#pragma unroll
    for (int ni = 0; ni < 4; ++ni)
#pragma unroll
      for (int rg = 0; rg < 4; ++rg) {
        int m = m0 + wm * 128 + mi * 16 + quad * 4 + rg;
        int n = n0 + wn * 64 + ni * 16 + ml;
        float v = acc[mi][ni][rg];
        if constexpr (MODE == 0) {
          int pl = n >> 6, col = n & 63;
          outB[(size_t)pl * NTOK * HS_ + (size_t)m * HS_ + col] = f2bf(v);
        } else if constexpr (MODE == 1) {
          if (m < n_e) {
            float hv = v + bias[e * DFF + n];
            outB[(size_t)(off + m) * DFF + n] = f2bf(fmaxf(hv, 0.f));
          }
        } else {
          if (m < n_e) {
            outB[(size_t)(off + m) * 1024 + n] = f2bf(v + bias[e * 1024 + n]);
          }
        }
      }
}

// ---------------------------------------------------------------- attention (bf16 MFMA flash)
__global__ __launch_bounds__(256) void attn_kernel(const u16* __restrict__ qkv,
                                                   const u16* __restrict__ Vt,
                                                   float* __restrict__ attn_out) {
  int qt = blockIdx.x, bh = blockIdx.y;
  int b = bh >> 4, h = bh & 15;
  int q0 = qt * 64;
  const u16* Qg = qkv + (size_t)h * NTOK * HS_ + (size_t)b * T_ * HS_;
  const u16* Kg = qkv + (size_t)(16 + h) * NTOK * HS_ + (size_t)b * T_ * HS_;
  const u16* Vp = Vt + (size_t)bh * HS_ * T_;
  __shared__ __align__(16) u16 Qs[64 * 72];
  __shared__ __align__(16) u16 Ks[64 * 72];
  __shared__ __align__(16) u16 Vs[64 * 72];   // Vs[c][j]
  __shared__ __align__(16) u16 Ps[64 * 72];   // wave w uses rows w*16..w*16+15
  int tid = threadIdx.x, lane = tid & 63, wave = tid >> 6;
  int ml = lane & 15, quad = lane >> 4;

  for (int i = tid; i < 512; i += 256) {
    int r = i >> 3, c = (i & 7) * 8;
    *(uint4*)&Qs[r * 72 + c] = *(const uint4*)(Qg + (size_t)(q0 + r) * HS_ + c);
  }

  f4 acc_o[4];
  float m_[4], l_[4];
#pragma unroll
  for (int i = 0; i < 4; ++i) {
    acc_o[i] = (f4){0.f, 0.f, 0.f, 0.f};
    m_[i] = -1e30f; l_[i] = 0.f;
  }

  for (int ck = 0; ck <= qt; ++ck) {
    int kv0 = ck * 64;
    __syncthreads();
    for (int i = tid; i < 512; i += 256) {
      int r = i >> 3, c = (i & 7) * 8;
      *(uint4*)&Ks[r * 72 + c] = *(const uint4*)(Kg + (size_t)(kv0 + r) * HS_ + c);
      *(uint4*)&Vs[r * 72 + c] = *(const uint4*)(Vp + (size_t)r * T_ + kv0 + c);
    }
    __syncthreads();

    // S = Q K^T (16x64 per wave)
    f4 sacc[4];
#pragma unroll
    for (int nt = 0; nt < 4; ++nt) sacc[nt] = (f4){0.f, 0.f, 0.f, 0.f};
#pragma unroll
    for (int kk = 0; kk < 64; kk += 32) {
      bf8 a = *(const bf8*)&Qs[(wave * 16 + ml) * 72 + kk + quad * 8];
#pragma unroll
      for (int nt = 0; nt < 4; ++nt) {
        bf8 bk = *(const bf8*)&Ks[(nt * 16 + ml) * 72 + kk + quad * 8];
        sacc[nt] = mfma16(a, bk, sacc[nt]);
      }
    }

    // online softmax; C-layout: row = quad*4+rg (strip-local), col = nt*16+ml
    bool dm = (kv0 == q0);  // only the diagonal chunk needs masking
    float pv[4][4], mx[4];
#pragma unroll
    for (int rg = 0; rg < 4; ++rg) {
      int gq = q0 + wave * 16 + quad * 4 + rg;
      float mm = -1e30f;
#pragma unroll
      for (int nt = 0; nt < 4; ++nt) {
        float s = sacc[nt][rg] * 0.03125f;  // D^-0.5
        if (dm && (kv0 + nt * 16 + ml) > gq) s = -1e30f;
        pv[nt][rg] = s;
        mm = fmaxf(mm, s);
      }
      mx[rg] = mm;
    }
#pragma unroll
    for (int off = 1; off < 16; off <<= 1)
#pragma unroll
      for (int rg = 0; rg < 4; ++rg) mx[rg] = fmaxf(mx[rg], __shfl_xor(mx[rg], off));

    float al[4], rs[4];
#pragma unroll
    for (int rg = 0; rg < 4; ++rg) {
      float mn = fmaxf(m_[rg], mx[rg]);
      al[rg] = __expf(m_[rg] - mn);
      m_[rg] = mn;
      float r = 0.f;
#pragma unroll
      for (int nt = 0; nt < 4; ++nt) {
        float ev = __expf(pv[nt][rg] - mn);
        pv[nt][rg] = ev;
        r += ev;
      }
      rs[rg] = r;
    }
#pragma unroll
    for (int off = 1; off < 16; off <<= 1)
#pragma unroll
      for (int rg = 0; rg < 4; ++rg) rs[rg] += __shfl_xor(rs[rg], off);

#pragma unroll
    for (int rg = 0; rg < 4; ++rg) {
      l_[rg] = al[rg] * l_[rg] + rs[rg];
#pragma unroll
      for (int nt = 0; nt < 4; ++nt) {
        acc_o[nt][rg] *= al[rg];
        Ps[(wave * 16 + quad * 4 + rg) * 72 + nt * 16 + ml] = f2bf(pv[nt][rg]);
      }
    }

    // PV: A = Ps strip (wave-local; in-wave LDS ordering suffices), B = Vs
#pragma unroll
    for (int kk = 0; kk < 64; kk += 32) {
      bf8 a = *(const bf8*)&Ps[(wave * 16 + ml) * 72 + kk + quad * 8];
#pragma unroll
      for (int ci = 0; ci < 4; ++ci) {
        bf8 bv = *(const bf8*)&Vs[(ci * 16 + ml) * 72 + kk + quad * 8];
        acc_o[ci] = mfma16(a, bv, acc_o[ci]);
      }
    }
  }

#pragma unroll
  for (int rg = 0; rg < 4; ++rg) {
    float inv = 1.f / l_[rg];
    int gq = q0 + wave * 16 + quad * 4 + rg;
    float* orow = attn_out + (size_t)(b * T_ + gq) * D_ + h * HS_;
#pragma unroll
    for (int ci = 0; ci < 4; ++ci) orow[ci * 16 + ml] = acc_o[ci][rg] * inv;
  }
}

// ---------------------------------------------------------------- final: out = x + LN(attn) + LN(moe)
__global__ __launch_bounds__(256) void final_kernel(
    const float* __restrict__ x, const float* __restrict__ attn,
    const u16* __restrict__ Y, const int* __restrict__ rowmap,
    const float* __restrict__ wgt,
    const float* __restrict__ g1, const float* __restrict__ be1,
    const float* __restrict__ g2, const float* __restrict__ be2,
    float* __restrict__ out) {
  int t = blockIdx.x, tid = threadIdx.x;
  int lane = tid & 63, wave = tid >> 6;
  float4 av = ((const float4*)(attn + (size_t)t * D_))[tid];
  int r0 = rowmap[2 * t], r1 = rowmap[2 * t + 1];
  float w0 = wgt[2 * t], w1 = wgt[2 * t + 1];
  ushort4 y0 = ((const ushort4*)(Y + (size_t)r0 * D_))[tid];
  ushort4 y1 = ((const ushort4*)(Y + (size_t)r1 * D_))[tid];
  float4 mv;
  mv.x = w0 * bf2f(y0.x) + w1 * bf2f(y1.x);
  mv.y = w0 * bf2f(y0.y) + w1 * bf2f(y1.y);
  mv.z = w0 * bf2f(y0.z) + w1 * bf2f(y1.z);
  mv.w = w0 * bf2f(y0.w) + w1 * bf2f(y1.w);

  float sa = av.x + av.y + av.z + av.w;
  float qa = av.x * av.x + av.y * av.y + av.z * av.z + av.w * av.w;
  float sm = mv.x + mv.y + mv.z + mv.w;
  float qm = mv.x * mv.x + mv.y * mv.y + mv.z * mv.z + mv.w * mv.w;
#pragma unroll
  for (int off = 1; off < 64; off <<= 1) {
    sa += __shfl_xor(sa, off);
    qa += __shfl_xor(qa, off);
    sm += __shfl_xor(sm, off);
    qm += __shfl_xor(qm, off);
  }
  __shared__ float red[4][4];
  if (lane == 0) { red[wave][0] = sa; red[wave][1] = qa; red[wave][2] = sm; red[wave][3] = qm; }
  __syncthreads();
  sa = red[0][0] + red[1][0] + red[2][0] + red[3][0];
  qa = red[0][1] + red[1][1] + red[2][1] + red[3][1];
  sm = red[0][2] + red[1][2] + red[2][2] + red[3][2];
  qm = red[0][3] + red[1][3] + red[2][3] + red[3][3];
  const float inv_d = 1.f / 1024.f;
  float mu1 = sa * inv_d, var1 = qa * inv_d - mu1 * mu1;
  float mu2 = sm * inv_d, var2 = qm * inv_d - mu2 * mu2;
  float rs1 = rsqrtf(var1 + 1e-5f), rs2 = rsqrtf(var2 + 1e-5f);

  float4 xv = ((const float4*)(x + (size_t)t * D_))[tid];
  float4 g1v = ((const float4*)g1)[tid], b1v = ((const float4*)be1)[tid];
  float4 g2v = ((const float4*)g2)[tid], b2v = ((const float4*)be2)[tid];
  float4 o;
  o.x = xv.x + (av.x - mu1) * rs1 * g1v.x + b1v.x + (mv.x - mu2) * rs2 * g2v.x + b2v.x;
  o.y = xv.y + (av.y - mu1) * rs1 * g1v.y + b1v.y + (mv.y - mu2) * rs2 * g2v.y + b2v.y;
  o.z = xv.z + (av.z - mu1) * rs1 * g1v.z + b1v.z + (mv.z - mu2) * rs2 * g2v.z + b2v.z;
  o.w = xv.w + (av.w - mu1) * rs1 * g1v.w + b1v.w + (mv.w - mu2) * rs2 * g2v.w + b2v.w;
  ((float4*)(out + (size_t)t * D_))[tid] = o;
}

// ---------------------------------------------------------------- launch
extern "C" void kernel_launch(void* const* d_in, const int* in_sizes, int n_in,
                              void* d_out, int out_size, void* d_ws, size_t ws_size,
                              hipStream_t stream) {
  const float* x   = (const float*)d_in[0];
  const float* Wq  = (const float*)d_in[1];
  const float* Wk  = (const float*)d_in[2];
  const float* Wv  = (const float*)d_in[3];
  const float* Wg  = (const float*)d_in[4];
  const float* W1  = (const float*)d_in[5];
  const float* b1  = (const float*)d_in[6];
  const float* W2  = (const float*)d_in[7];
  const float* b2  = (const float*)d_in[8];
  const float* g1  = (const float*)d_in[9];
  const float* be1 = (const float*)d_in[10];
  const float* g2  = (const float*)d_in[11];
  const float* be2 = (const float*)d_in[12];
  float* out = (float*)d_out;

  char* ws = (char*)d_ws;
  size_t off = 0;
  auto alloc = [&](size_t bytes) -> void* {
    void* p = ws + off;
    off = (off + bytes + 255) & ~(size_t)255;
    return p;
  };
  u16*   xbf    = (u16*)alloc((size_t)NTOK * D_ * 2);          // 16.8 MB
  u16*   wqkvt  = (u16*)alloc((size_t)48 * 64 * 1024 * 2);     // 6.3 MB  [3072][1024]
  u16*   w1t    = (u16*)alloc((size_t)E_ * DFF * 1024 * 2);    // 67 MB   [e][4096][1024]
  u16*   w2t    = (u16*)alloc((size_t)E_ * 1024 * DFF * 2);    // 67 MB   [e][1024][4096]
  u16*   qkv    = (u16*)alloc((size_t)48 * NTOK * HS_ * 2);    // 50 MB   [mat*16+h][8192][64]
  float* attn   = (float*)alloc((size_t)NTOK * D_ * 4);        // 33.5 MB
  u16*   Hbuf   = (u16*)alloc((size_t)NROW * DFF * 2);         // 134 MB
  u16*   Ybuf   = (u16*)alloc((size_t)NROW * 1024 * 2);        // 33.5 MB
  int*   meta   = (int*)alloc(256);
  int*   sel    = (int*)alloc(NROW * 4);
  float* wgt    = (float*)alloc(NROW * 4);
  int*   gidx   = (int*)alloc(NROW * 4);
  float* gw     = (float*)alloc(NROW * 4);
  int*   rowmap = (int*)alloc(NROW * 4);
  // Vt aliases Hbuf: consumed by attn_kernel before gemm256<1> writes Hbuf.
  u16*   Vt     = Hbuf;  // 16.7 MB [bh][64][1024]
  (void)ws_size; (void)in_sizes; (void)n_in; (void)out_size; (void)gw;

  // dtype converts / transposes (weights -> bf16, K-contiguous "B^T" layout)
  cvt_x_kernel<<<NTOK * D_ / 1024, 256, 0, stream>>>(x, xbf);
  transpose_cvt_kernel<<<dim3(32, 2, 16), 256, 0, stream>>>(Wq, wqkvt, 1024, 64, 65536, 65536);
  transpose_cvt_kernel<<<dim3(32, 2, 16), 256, 0, stream>>>(Wk, wqkvt + 16 * 65536, 1024, 64, 65536, 65536);
  transpose_cvt_kernel<<<dim3(32, 2, 16), 256, 0, stream>>>(Wv, wqkvt + 32 * 65536, 1024, 64, 65536, 65536);
  transpose_cvt_kernel<<<dim3(32, 128, 8), 256, 0, stream>>>(W1, w1t, 1024, 4096, (size_t)1024 * 4096, (size_t)1024 * 4096);
  transpose_cvt_kernel<<<dim3(128, 32, 8), 256, 0, stream>>>(W2, w2t, 4096, 1024, (size_t)4096 * 1024, (size_t)4096 * 1024);

  // routing
  gating_kernel<<<NTOK / 4, 256, 0, stream>>>(x, Wg, sel, wgt);
  offsets_kernel<<<1, 256, 0, stream>>>(sel, meta);
  assign_kernel<<<E_, 256, 0, stream>>>(sel, wgt, meta, gidx, gw, rowmap);

  // attention branch: QKV as one 8192x3072x1024 GEMM, then V transpose, then flash
  gemm256<0><<<dim3(32, 12), 512, 0, stream>>>(xbf, wqkvt, qkv, nullptr, nullptr, nullptr, 1024);
  vtrans_kernel<<<dim3(32, 2, 128), 256, 0, stream>>>(qkv, Vt);
  attn_kernel<<<dim3(16, 128), 256, 0, stream>>>(qkv, Vt, attn);

  // MoE branch: compacted 256-row m-block grid (worst case 71 = 64 full + 7 partial)
  gemm256<1><<<dim3(72, 16), 512, 0, stream>>>(xbf, w1t, Hbuf, b1, meta, gidx, 1024);
  gemm256<2><<<dim3(72, 4), 512, 0, stream>>>(Hbuf, w2t, Ybuf, b2, meta, gidx, 4096);

  // out = x + LN(attn) + LN(moe)
  final_kernel<<<NTOK, 256, 0, stream>>>(x, attn, Ybuf, rowmap, wgt, g1, be1, g2, be2, out);
}

// Round 3
// 1112.990 us; speedup vs baseline: 1.1150x; 1.0700x over previous
//
#include <hip/hip_runtime.h>

// Problem constants
#define B_    8
#define T_    1024
#define D_    1024
#define H_    16
#define HS_   64
#define E_    8
#define DFF   4096
#define NTOK  8192    // B*T
#define NROW  16384   // NTOK * top-2

typedef unsigned short u16;
typedef unsigned int   u32;
typedef __attribute__((ext_vector_type(8))) short bf8;   // 8 bf16 in 4 VGPRs
typedef __attribute__((ext_vector_type(4))) float f4;    // MFMA accumulator

__device__ __forceinline__ u16 f2bf(float f) {
  u32 u = __float_as_uint(f);
  u32 r = (u + 0x7FFFu + ((u >> 16) & 1u)) >> 16;  // RNE
  return (u16)r;
}
__device__ __forceinline__ float bf2f(u16 h) {
  return __uint_as_float(((u32)h) << 16);
}

__device__ __forceinline__ f4 mfma16(bf8 a, bf8 b, f4 c) {
  return __builtin_amdgcn_mfma_f32_16x16x32_bf16(a, b, c, 0, 0, 0);
}

// async global->LDS, 16B per lane; LDS dest = wave-uniform base + lane*16
typedef const __attribute__((address_space(1))) void* gas_ptr;
typedef __attribute__((address_space(3))) void* las_ptr;
__device__ __forceinline__ void async16(const void* g, void* l) {
  __builtin_amdgcn_global_load_lds((gas_ptr)g, (las_ptr)l, 16, 0, 0);
}

// ---------------------------------------------------------------- converts
__global__ __launch_bounds__(256) void cvt_x_kernel(const float* __restrict__ x,
                                                    u16* __restrict__ xbf) {
  int i = blockIdx.x * 256 + threadIdx.x;  // float4 index
  float4 v = ((const float4*)x)[i];
  ushort4 o;
  o.x = f2bf(v.x); o.y = f2bf(v.y); o.z = f2bf(v.z); o.w = f2bf(v.w);
  ((ushort4*)xbf)[i] = o;
}

// src fp32 [R x C] -> dst bf16 [C x R], batched along z
__global__ __launch_bounds__(256) void transpose_cvt_kernel(
    const float* __restrict__ src, u16* __restrict__ dst,
    int R, int C, size_t sStride, size_t dStride) {
  __shared__ float t[32][33];
  src += (size_t)blockIdx.z * sStride;
  dst += (size_t)blockIdx.z * dStride;
  int r0 = blockIdx.x * 32, c0 = blockIdx.y * 32;
  int tx = threadIdx.x & 31, ty = threadIdx.x >> 5;  // ty 0..7
#pragma unroll
  for (int i = 0; i < 32; i += 8)
    t[ty + i][tx] = src[(size_t)(r0 + ty + i) * C + (c0 + tx)];
  __syncthreads();
#pragma unroll
  for (int i = 0; i < 32; i += 8)
    dst[(size_t)(c0 + ty + i) * R + (r0 + tx)] = f2bf(t[tx][ty + i]);
}

// V plane [t][c] -> Vt [bh][c][t] (bf16), for PV B-operand staging
__global__ __launch_bounds__(256) void vtrans_kernel(const u16* __restrict__ qkv,
                                                     u16* __restrict__ Vt) {
  __shared__ u16 t[32][33];
  int bh = blockIdx.z, b = bh >> 4, h = bh & 15;
  const u16* Vg = qkv + (size_t)(32 + h) * NTOK * HS_ + (size_t)b * T_ * HS_;
  u16* Vp = Vt + (size_t)bh * HS_ * T_;
  int t0 = blockIdx.x * 32, c0 = blockIdx.y * 32;
  int tx = threadIdx.x & 31, ty = threadIdx.x >> 5;
#pragma unroll
  for (int i = 0; i < 32; i += 8)
    t[ty + i][tx] = Vg[(size_t)(t0 + ty + i) * HS_ + c0 + tx];
  __syncthreads();
#pragma unroll
  for (int i = 0; i < 32; i += 8)
    Vp[(size_t)(c0 + ty + i) * T_ + t0 + tx] = t[tx][ty + i];
}

// ---------------------------------------------------------------- gating
// exact fp32 gating so top-2 selection matches the reference
__global__ __launch_bounds__(256) void gating_kernel(
    const float* __restrict__ x, const float* __restrict__ Wg,
    int* __restrict__ sel, float* __restrict__ wgt) {
  int wave = threadIdx.x >> 6, lane = threadIdx.x & 63;
  int t = blockIdx.x * 4 + wave;
  int e = lane & 7, grp = lane >> 3;
  const float* xr = x + (size_t)t * D_;
  float acc = 0.f;
  for (int i = 0; i < 128; ++i) {
    int d = grp + i * 8;
    acc += xr[d] * Wg[d * 8 + e];
  }
  acc += __shfl_xor(acc, 8);
  acc += __shfl_xor(acc, 16);
  acc += __shfl_xor(acc, 32);
  float lg[8];
#pragma unroll
  for (int j = 0; j < 8; ++j) lg[j] = __shfl(acc, j);
  int s0 = 0; float v0 = lg[0];
#pragma unroll
  for (int j = 1; j < 8; ++j) if (lg[j] > v0) { v0 = lg[j]; s0 = j; }
  int s1 = -1; float v1 = -3.4e38f;
#pragma unroll
  for (int j = 0; j < 8; ++j) if (j != s0 && lg[j] > v1) { v1 = lg[j]; s1 = j; }
  if (lane == 0) {
    float dd = __expf(v1 - v0);
    float w0 = 1.f / (1.f + dd);
    sel[2 * t]     = s0; sel[2 * t + 1] = s1;
    wgt[2 * t]     = w0; wgt[2 * t + 1] = dd * w0;
  }
}

// meta[0..7]=counts, meta[8..15]=row offsets, meta[16..23]=128-block prefix,
// meta[24]=total 128-blocks, meta[32..39]=256-block prefix, meta[40]=total 256-blocks
__global__ __launch_bounds__(256) void offsets_kernel(const int* __restrict__ sel,
                                                      int* __restrict__ meta) {
  __shared__ int hist[E_];
  int tid = threadIdx.x;
  if (tid < E_) hist[tid] = 0;
  __syncthreads();
  for (int i = tid; i < NROW; i += 256) atomicAdd(&hist[sel[i]], 1);
  __syncthreads();
  if (tid == 0) {
    int s = 0, mb = 0, mb2 = 0;
    for (int e = 0; e < E_; ++e) {
      int c = hist[e];
      meta[e] = c; meta[8 + e] = s; meta[16 + e] = mb; meta[32 + e] = mb2;
      s += c; mb += (c + 127) >> 7; mb2 += (c + 255) >> 8;
    }
    meta[24] = mb;
    meta[40] = mb2;
  }
}

// deterministic per-expert stable assignment via ballot scan
__global__ __launch_bounds__(256) void assign_kernel(
    const int* __restrict__ sel, const float* __restrict__ wgt,
    const int* __restrict__ meta, int* __restrict__ gidx,
    float* __restrict__ gw, int* __restrict__ rowmap) {
  int e = blockIdx.x, tid = threadIdx.x, lane = tid & 63, wv = tid >> 6;
  __shared__ int wsum[4];
  __shared__ int carry;
  if (tid == 0) carry = meta[8 + e];
  __syncthreads();
  for (int base = 0; base < NROW; base += 256) {
    int idx = base + tid;
    int f = (sel[idx] == e) ? 1 : 0;
    unsigned long long mask = __ballot(f);
    int pre = __popcll(mask & ((1ull << lane) - 1ull));
    if (lane == 0) wsum[wv] = __popcll(mask);
    __syncthreads();
    int woff = 0;
    for (int w = 0; w < wv; ++w) woff += wsum[w];
    int cb = carry;
    if (f) {
      int pos = cb + woff + pre;
      gidx[pos] = idx >> 1;
      gw[pos] = wgt[idx];
      rowmap[idx] = pos;
    }
    __syncthreads();
    if (tid == 0) carry = cb + wsum[0] + wsum[1] + wsum[2] + wsum[3];
    __syncthreads();
  }
}

// ---------------------------------------------------------------- GEMM (bf16 MFMA, 256^2 8-wave, static dual-buffer)
// C[m][n] = sum_k A[m][k] * Bt[n][k]; tile 256x256, BK=64, 8 waves as 2x4,
// each wave 128x64 output = acc[8][4]. LDS: FOUR distinct static 32 KiB
// buffers (As0/As1/Bs0/Bs1) so the waitcnt pass can disambiguate ds_reads
// from outstanding global_load_lds DMAs (runtime-indexed As[c] defeats AA
// and triggers conservative vmcnt waits -> R1/R2 stall). K-loop unrolled x2
// so every buffer reference is compile-time static.
//
// Per K-tile (one __syncthreads each):
//   ds_read kk0 frags (12)   <- zero DMAs outstanding at tile start: no wait
//   issue 8 stage DMAs (t+1) -> the *other* buffer pair
//   32 MFMA kk0              <- ~1240 cyc, covers any conservative wait
//   ds_read kk1 frags (12)
//   32 MFMA kk1
//   __syncthreads()          <- implicit vmcnt(0): stage issued ~2500 cyc ago
// XOR source-swizzle staging (verified): LDS[row][chunk] holds logical chunk
// ^(row&7); staging lane fetches global chunk (l&7)^(l>>3); reads XOR row&7.
//
// MODE 0: QKV  A=xbf[8192x1024], Bt=wqkvt[3072x1024], out planes qkv[48][8192][64]
// MODE 1: MoE1 A=xbf gathered via gidx, Bt=w1t[e], out H bf16 (+bias,relu)
// MODE 2: MoE2 A=Hbuf rows, Bt=w2t[e], out Y bf16 (+bias)
template <int MODE>
__global__ __launch_bounds__(512) void gemm256(
    const u16* __restrict__ A, const u16* __restrict__ Bt,
    u16* __restrict__ outB, const float* __restrict__ bias,
    const int* __restrict__ meta, const int* __restrict__ gidx, int K) {
  int n0 = blockIdx.y * 256;
  int n_e = 0, off = 0, m0, e = 0;
  const u16* Ap = A;
  const u16* Bp = Bt;
  if constexpr (MODE != 0) {
    int xb = blockIdx.x;
#pragma unroll
    for (int j = 1; j < 8; ++j) if (meta[32 + j] <= xb) e = j;
    n_e = meta[e];
    off = meta[8 + e];
    m0 = (xb - meta[32 + e]) * 256;
    if (m0 >= n_e) return;  // also catches xb >= meta[40]
    if constexpr (MODE == 1) {
      Bp = Bt + (size_t)e * DFF * 1024;
    } else {
      Ap = A + (size_t)off * DFF;
      Bp = Bt + (size_t)e * 1024 * DFF;
    }
  } else {
    m0 = blockIdx.x * 256;
  }

  __shared__ __align__(16) u16 As0[256 * 64];   // 32 KiB each
  __shared__ __align__(16) u16 As1[256 * 64];
  __shared__ __align__(16) u16 Bs0[256 * 64];
  __shared__ __align__(16) u16 Bs1[256 * 64];

  int tid = threadIdx.x, lane = tid & 63, w = tid >> 6;  // 8 waves
  int wm = w >> 2, wn = w & 3;
  int ml = lane & 15, quad = lane >> 4;
  int lrow = lane >> 3;                      // 0..7
  int gcol = ((lane & 7) ^ lrow) * 8;        // source-swizzled chunk col (u16)

  // per-lane global row pointers for the 4 staging slices (64 rows each)
  const u16* aptr[4];
  const u16* bptr[4];
#pragma unroll
  for (int i = 0; i < 4; ++i) {
    int ra = m0 + i * 64 + w * 8 + lrow;
    if constexpr (MODE == 1) {
      int rr = ra < n_e ? ra : n_e - 1;
      aptr[i] = Ap + (size_t)gidx[off + rr] * 1024 + gcol;
    } else if constexpr (MODE == 2) {
      int rr = ra < n_e ? ra : n_e - 1;
      aptr[i] = Ap + (size_t)rr * DFF + gcol;
    } else {
      aptr[i] = Ap + (size_t)ra * 1024 + gcol;
    }
    bptr[i] = Bp + (size_t)(n0 + i * 64 + w * 8 + lrow) * K + gcol;
  }

  const int NT = K >> 6;
  int mq = ml & 7;  // row&7 for fragment rows (frag bases are multiples of 8)

  f4 acc[8][4];
#pragma unroll
  for (int i = 0; i < 8; ++i)
#pragma unroll
    for (int j = 0; j < 4; ++j) acc[i][j] = (f4){0.f, 0.f, 0.f, 0.f};

  // one K-tile step: compute from (Ac,Bc), prefetch tile tn into (An,Bn)
  auto do_tile = [&](const u16* __restrict__ Ac, const u16* __restrict__ Bc,
                     u16* __restrict__ An, u16* __restrict__ Bn, int tn) {
    bf8 af[8], bfr[4];
    // kk0 fragment reads (no DMAs outstanding at tile entry)
#pragma unroll
    for (int mi = 0; mi < 8; ++mi)
      af[mi] = *(const bf8*)&Ac[(wm * 128 + mi * 16 + ml) * 64 + (quad ^ mq) * 8];
#pragma unroll
    for (int ni = 0; ni < 4; ++ni)
      bfr[ni] = *(const bf8*)&Bc[(wn * 64 + ni * 16 + ml) * 64 + (quad ^ mq) * 8];
    // issue next-tile staging DMAs into the other (statically named) buffers
    if (tn < NT) {
#pragma unroll
      for (int i = 0; i < 4; ++i)
        async16(aptr[i] + tn * 64, &An[(i * 64 + w * 8) * 64]);
#pragma unroll
      for (int i = 0; i < 4; ++i)
        async16(bptr[i] + tn * 64, &Bn[(i * 64 + w * 8) * 64]);
    }
    // kk0 MFMA cluster
#pragma unroll
    for (int mi = 0; mi < 8; ++mi)
#pragma unroll
      for (int ni = 0; ni < 4; ++ni)
        acc[mi][ni] = mfma16(af[mi], bfr[ni], acc[mi][ni]);
    // kk1 fragment reads
#pragma unroll
    for (int mi = 0; mi < 8; ++mi)
      af[mi] = *(const bf8*)&Ac[(wm * 128 + mi * 16 + ml) * 64 + ((4 + quad) ^ mq) * 8];
#pragma unroll
    for (int ni = 0; ni < 4; ++ni)
      bfr[ni] = *(const bf8*)&Bc[(wn * 64 + ni * 16 + ml) * 64 + ((4 + quad) ^ mq) * 8];
    // kk1 MFMA cluster
#pragma unroll
    for (int mi = 0; mi < 8; ++mi)
#pragma unroll
      for (int ni = 0; ni < 4; ++ni)
        acc[mi][ni] = mfma16(af[mi], bfr[ni], acc[mi][ni]);
    __syncthreads();  // drains this tile's prefetch; all readers done
  };

  // prologue: stage tile 0 into buffer 0
#pragma unroll
  for (int i = 0; i < 4; ++i) async16(aptr[i], &As0[(i * 64 + w * 8) * 64]);
#pragma unroll
  for (int i = 0; i < 4; ++i) async16(bptr[i], &Bs0[(i * 64 + w * 8) * 64]);
  __syncthreads();

  for (int t = 0; t < NT; t += 2) {   // NT is even (16 or 64)
    do_tile(As0, Bs0, As1, Bs1, t + 1);
    do_tile(As1, Bs1, As0, Bs0, t + 2);
  }

#pragma unroll
  for (int mi = 0; mi < 8; ++mi)
#pragma unroll
    for (int ni = 0; ni < 4; ++ni)
#pragma unroll
      for (int rg = 0; rg < 4; ++rg) {
        int m = m0 + wm * 128 + mi * 16 + quad * 4 + rg;
        int n = n0 + wn * 64 + ni * 16 + ml;
        float v = acc[mi][ni][rg];
        if constexpr (MODE == 0) {
          int pl = n >> 6, col = n & 63;
          outB[(size_t)pl * NTOK * HS_ + (size_t)m * HS_ + col] = f2bf(v);
        } else if constexpr (MODE == 1) {
          if (m < n_e) {
            float hv = v + bias[e * DFF + n];
            outB[(size_t)(off + m) * DFF + n] = f2bf(fmaxf(hv, 0.f));
          }
        } else {
          if (m < n_e) {
            outB[(size_t)(off + m) * 1024 + n] = f2bf(v + bias[e * 1024 + n]);
          }
        }
      }
}

// ---------------------------------------------------------------- attention (bf16 MFMA flash)
__global__ __launch_bounds__(256) void attn_kernel(const u16* __restrict__ qkv,
                                                   const u16* __restrict__ Vt,
                                                   float* __restrict__ attn_out) {
  int qt = blockIdx.x, bh = blockIdx.y;
  int b = bh >> 4, h = bh & 15;
  int q0 = qt * 64;
  const u16* Qg = qkv + (size_t)h * NTOK * HS_ + (size_t)b * T_ * HS_;
  const u16* Kg = qkv + (size_t)(16 + h) * NTOK * HS_ + (size_t)b * T_ * HS_;
  const u16* Vp = Vt + (size_t)bh * HS_ * T_;
  __shared__ __align__(16) u16 Qs[64 * 72];
  __shared__ __align__(16) u16 Ks[64 * 72];
  __shared__ __align__(16) u16 Vs[64 * 72];   // Vs[c][j]
  __shared__ __align__(16) u16 Ps[64 * 72];   // wave w uses rows w*16..w*16+15
  int tid = threadIdx.x, lane = tid & 63, wave = tid >> 6;
  int ml = lane & 15, quad = lane >> 4;

  for (int i = tid; i < 512; i += 256) {
    int r = i >> 3, c = (i & 7) * 8;
    *(uint4*)&Qs[r * 72 + c] = *(const uint4*)(Qg + (size_t)(q0 + r) * HS_ + c);
  }

  f4 acc_o[4];
  float m_[4], l_[4];
#pragma unroll
  for (int i = 0; i < 4; ++i) {
    acc_o[i] = (f4){0.f, 0.f, 0.f, 0.f};
    m_[i] = -1e30f; l_[i] = 0.f;
  }

  for (int ck = 0; ck <= qt; ++ck) {
    int kv0 = ck * 64;
    __syncthreads();
    for (int i = tid; i < 512; i += 256) {
      int r = i >> 3, c = (i & 7) * 8;
      *(uint4*)&Ks[r * 72 + c] = *(const uint4*)(Kg + (size_t)(kv0 + r) * HS_ + c);
      *(uint4*)&Vs[r * 72 + c] = *(const uint4*)(Vp + (size_t)r * T_ + kv0 + c);
    }
    __syncthreads();

    // S = Q K^T (16x64 per wave)
    f4 sacc[4];
#pragma unroll
    for (int nt = 0; nt < 4; ++nt) sacc[nt] = (f4){0.f, 0.f, 0.f, 0.f};
#pragma unroll
    for (int kk = 0; kk < 64; kk += 32) {
      bf8 a = *(const bf8*)&Qs[(wave * 16 + ml) * 72 + kk + quad * 8];
#pragma unroll
      for (int nt = 0; nt < 4; ++nt) {
        bf8 bk = *(const bf8*)&Ks[(nt * 16 + ml) * 72 + kk + quad * 8];
        sacc[nt] = mfma16(a, bk, sacc[nt]);
      }
    }

    // online softmax; C-layout: row = quad*4+rg (strip-local), col = nt*16+ml
    bool dm = (kv0 == q0);  // only the diagonal chunk needs masking
    float pv[4][4], mx[4];
#pragma unroll
    for (int rg = 0; rg < 4; ++rg) {
      int gq = q0 + wave * 16 + quad * 4 + rg;
      float mm = -1e30f;
#pragma unroll
      for (int nt = 0; nt < 4; ++nt) {
        float s = sacc[nt][rg] * 0.03125f;  // D^-0.5
        if (dm && (kv0 + nt * 16 + ml) > gq) s = -1e30f;
        pv[nt][rg] = s;
        mm = fmaxf(mm, s);
      }
      mx[rg] = mm;
    }
#pragma unroll
    for (int off = 1; off < 16; off <<= 1)
#pragma unroll
      for (int rg = 0; rg < 4; ++rg) mx[rg] = fmaxf(mx[rg], __shfl_xor(mx[rg], off));

    float al[4], rs[4];
#pragma unroll
    for (int rg = 0; rg < 4; ++rg) {
      float mn = fmaxf(m_[rg], mx[rg]);
      al[rg] = __expf(m_[rg] - mn);
      m_[rg] = mn;
      float r = 0.f;
#pragma unroll
      for (int nt = 0; nt < 4; ++nt) {
        float ev = __expf(pv[nt][rg] - mn);
        pv[nt][rg] = ev;
        r += ev;
      }
      rs[rg] = r;
    }
#pragma unroll
    for (int off = 1; off < 16; off <<= 1)
#pragma unroll
      for (int rg = 0; rg < 4; ++rg) rs[rg] += __shfl_xor(rs[rg], off);

#pragma unroll
    for (int rg = 0; rg < 4; ++rg) {
      l_[rg] = al[rg] * l_[rg] + rs[rg];
#pragma unroll
      for (int nt = 0; nt < 4; ++nt) {
        acc_o[nt][rg] *= al[rg];
        Ps[(wave * 16 + quad * 4 + rg) * 72 + nt * 16 + ml] = f2bf(pv[nt][rg]);
      }
    }

    // PV: A = Ps strip (wave-local; in-wave LDS ordering suffices), B = Vs
#pragma unroll
    for (int kk = 0; kk < 64; kk += 32) {
      bf8 a = *(const bf8*)&Ps[(wave * 16 + ml) * 72 + kk + quad * 8];
#pragma unroll
      for (int ci = 0; ci < 4; ++ci) {
        bf8 bv = *(const bf8*)&Vs[(ci * 16 + ml) * 72 + kk + quad * 8];
        acc_o[ci] = mfma16(a, bv, acc_o[ci]);
      }
    }
  }

#pragma unroll
  for (int rg = 0; rg < 4; ++rg) {
    float inv = 1.f / l_[rg];
    int gq = q0 + wave * 16 + quad * 4 + rg;
    float* orow = attn_out + (size_t)(b * T_ + gq) * D_ + h * HS_;
#pragma unroll
    for (int ci = 0; ci < 4; ++ci) orow[ci * 16 + ml] = acc_o[ci][rg] * inv;
  }
}

// ---------------------------------------------------------------- final: out = x + LN(attn) + LN(moe)
__global__ __launch_bounds__(256) void final_kernel(
    const float* __restrict__ x, const float* __restrict__ attn,
    const u16* __restrict__ Y, const int* __restrict__ rowmap,
    const float* __restrict__ wgt,
    const float* __restrict__ g1, const float* __restrict__ be1,
    const float* __restrict__ g2, const float* __restrict__ be2,
    float* __restrict__ out) {
  int t = blockIdx.x, tid = threadIdx.x;
  int lane = tid & 63, wave = tid >> 6;
  float4 av = ((const float4*)(attn + (size_t)t * D_))[tid];
  int r0 = rowmap[2 * t], r1 = rowmap[2 * t + 1];
  float w0 = wgt[2 * t], w1 = wgt[2 * t + 1];
  ushort4 y0 = ((const ushort4*)(Y + (size_t)r0 * D_))[tid];
  ushort4 y1 = ((const ushort4*)(Y + (size_t)r1 * D_))[tid];
  float4 mv;
  mv.x = w0 * bf2f(y0.x) + w1 * bf2f(y1.x);
  mv.y = w0 * bf2f(y0.y) + w1 * bf2f(y1.y);
  mv.z = w0 * bf2f(y0.z) + w1 * bf2f(y1.z);
  mv.w = w0 * bf2f(y0.w) + w1 * bf2f(y1.w);

  float sa = av.x + av.y + av.z + av.w;
  float qa = av.x * av.x + av.y * av.y + av.z * av.z + av.w * av.w;
  float sm = mv.x + mv.y + mv.z + mv.w;
  float qm = mv.x * mv.x + mv.y * mv.y + mv.z * mv.z + mv.w * mv.w;
#pragma unroll
  for (int off = 1; off < 64; off <<= 1) {
    sa += __shfl_xor(sa, off);
    qa += __shfl_xor(qa, off);
    sm += __shfl_xor(sm, off);
    qm += __shfl_xor(qm, off);
  }
  __shared__ float red[4][4];
  if (lane == 0) { red[wave][0] = sa; red[wave][1] = qa; red[wave][2] = sm; red[wave][3] = qm; }
  __syncthreads();
  sa = red[0][0] + red[1][0] + red[2][0] + red[3][0];
  qa = red[0][1] + red[1][1] + red[2][1] + red[3][1];
  sm = red[0][2] + red[1][2] + red[2][2] + red[3][2];
  qm = red[0][3] + red[1][3] + red[2][3] + red[3][3];
  const float inv_d = 1.f / 1024.f;
  float mu1 = sa * inv_d, var1 = qa * inv_d - mu1 * mu1;
  float mu2 = sm * inv_d, var2 = qm * inv_d - mu2 * mu2;
  float rs1 = rsqrtf(var1 + 1e-5f), rs2 = rsqrtf(var2 + 1e-5f);

  float4 xv = ((const float4*)(x + (size_t)t * D_))[tid];
  float4 g1v = ((const float4*)g1)[tid], b1v = ((const float4*)be1)[tid];
  float4 g2v = ((const float4*)g2)[tid], b2v = ((const float4*)be2)[tid];
  float4 o;
  o.x = xv.x + (av.x - mu1) * rs1 * g1v.x + b1v.x + (mv.x - mu2) * rs2 * g2v.x + b2v.x;
  o.y = xv.y + (av.y - mu1) * rs1 * g1v.y + b1v.y + (mv.y - mu2) * rs2 * g2v.y + b2v.y;
  o.z = xv.z + (av.z - mu1) * rs1 * g1v.z + b1v.z + (mv.z - mu2) * rs2 * g2v.z + b2v.z;
  o.w = xv.w + (av.w - mu1) * rs1 * g1v.w + b1v.w + (mv.w - mu2) * rs2 * g2v.w + b2v.w;
  ((float4*)(out + (size_t)t * D_))[tid] = o;
}

// ---------------------------------------------------------------- launch
extern "C" void kernel_launch(void* const* d_in, const int* in_sizes, int n_in,
                              void* d_out, int out_size, void* d_ws, size_t ws_size,
                              hipStream_t stream) {
  const float* x   = (const float*)d_in[0];
  const float* Wq  = (const float*)d_in[1];
  const float* Wk  = (const float*)d_in[2];
  const float* Wv  = (const float*)d_in[3];
  const float* Wg  = (const float*)d_in[4];
  const float* W1  = (const float*)d_in[5];
  const float* b1  = (const float*)d_in[6];
  const float* W2  = (const float*)d_in[7];
  const float* b2  = (const float*)d_in[8];
  const float* g1  = (const float*)d_in[9];
  const float* be1 = (const float*)d_in[10];
  const float* g2  = (const float*)d_in[11];
  const float* be2 = (const float*)d_in[12];
  float* out = (float*)d_out;

  char* ws = (char*)d_ws;
  size_t off = 0;
  auto alloc = [&](size_t bytes) -> void* {
    void* p = ws + off;
    off = (off + bytes + 255) & ~(size_t)255;
    return p;
  };
  u16*   xbf    = (u16*)alloc((size_t)NTOK * D_ * 2);          // 16.8 MB
  u16*   wqkvt  = (u16*)alloc((size_t)48 * 64 * 1024 * 2);     // 6.3 MB  [3072][1024]
  u16*   w1t    = (u16*)alloc((size_t)E_ * DFF * 1024 * 2);    // 67 MB   [e][4096][1024]
  u16*   w2t    = (u16*)alloc((size_t)E_ * 1024 * DFF * 2);    // 67 MB   [e][1024][4096]
  u16*   qkv    = (u16*)alloc((size_t)48 * NTOK * HS_ * 2);    // 50 MB   [mat*16+h][8192][64]
  float* attn   = (float*)alloc((size_t)NTOK * D_ * 4);        // 33.5 MB
  u16*   Hbuf   = (u16*)alloc((size_t)NROW * DFF * 2);         // 134 MB
  u16*   Ybuf   = (u16*)alloc((size_t)NROW * 1024 * 2);        // 33.5 MB
  int*   meta   = (int*)alloc(256);
  int*   sel    = (int*)alloc(NROW * 4);
  float* wgt    = (float*)alloc(NROW * 4);
  int*   gidx   = (int*)alloc(NROW * 4);
  float* gw     = (float*)alloc(NROW * 4);
  int*   rowmap = (int*)alloc(NROW * 4);
  // Vt aliases Hbuf: consumed by attn_kernel before gemm256<1> writes Hbuf.
  u16*   Vt     = Hbuf;  // 16.7 MB [bh][64][1024]
  (void)ws_size; (void)in_sizes; (void)n_in; (void)out_size; (void)gw;

  // dtype converts / transposes (weights -> bf16, K-contiguous "B^T" layout)
  cvt_x_kernel<<<NTOK * D_ / 1024, 256, 0, stream>>>(x, xbf);
  transpose_cvt_kernel<<<dim3(32, 2, 16), 256, 0, stream>>>(Wq, wqkvt, 1024, 64, 65536, 65536);
  transpose_cvt_kernel<<<dim3(32, 2, 16), 256, 0, stream>>>(Wk, wqkvt + 16 * 65536, 1024, 64, 65536, 65536);
  transpose_cvt_kernel<<<dim3(32, 2, 16), 256, 0, stream>>>(Wv, wqkvt + 32 * 65536, 1024, 64, 65536, 65536);
  transpose_cvt_kernel<<<dim3(32, 128, 8), 256, 0, stream>>>(W1, w1t, 1024, 4096, (size_t)1024 * 4096, (size_t)1024 * 4096);
  transpose_cvt_kernel<<<dim3(128, 32, 8), 256, 0, stream>>>(W2, w2t, 4096, 1024, (size_t)4096 * 1024, (size_t)4096 * 1024);

  // routing
  gating_kernel<<<NTOK / 4, 256, 0, stream>>>(x, Wg, sel, wgt);
  offsets_kernel<<<1, 256, 0, stream>>>(sel, meta);
  assign_kernel<<<E_, 256, 0, stream>>>(sel, wgt, meta, gidx, gw, rowmap);

  // attention branch: QKV as one 8192x3072x1024 GEMM, then V transpose, then flash
  gemm256<0><<<dim3(32, 12), 512, 0, stream>>>(xbf, wqkvt, qkv, nullptr, nullptr, nullptr, 1024);
  vtrans_kernel<<<dim3(32, 2, 128), 256, 0, stream>>>(qkv, Vt);
  attn_kernel<<<dim3(16, 128), 256, 0, stream>>>(qkv, Vt, attn);

  // MoE branch: compacted 256-row m-block grid (worst case 71 = 64 full + 7 partial)
  gemm256<1><<<dim3(72, 16), 512, 0, stream>>>(xbf, w1t, Hbuf, b1, meta, gidx, 1024);
  gemm256<2><<<dim3(72, 4), 512, 0, stream>>>(Hbuf, w2t, Ybuf, b2, meta, gidx, 4096);

  // out = x + LN(attn) + LN(moe)
  final_kernel<<<NTOK, 256, 0, stream>>>(x, attn, Ybuf, rowmap, wgt, g1, be1, g2, be2, out);
}